// Round 6
// baseline (529.318 us; speedup 1.0000x reference)
//
#include <hip/hip_runtime.h>
#include <hip/hip_bf16.h>

// Problem: B=32, S=2048, ENC=1024, DEC=512
//   h_proj[b,e]   = sum_d hidden[b,d] * W[e,d]            (Wh = W[:, :512])
//   e_proj[b,s,d] = sum_e enc[b,s,e] * W[d, 512+e]        (We = W[:, 512:])
//   energy = tanh(e_proj + h_proj + bias); scores = v . energy; attn = softmax_s

typedef __attribute__((ext_vector_type(8))) short bf16x8;
typedef __attribute__((ext_vector_type(4))) float f32x4;

__device__ __forceinline__ ushort f2bf(float x) {
    __hip_bfloat16 h = __float2bfloat16(x);
    return *reinterpret_cast<ushort*>(&h);
}

__device__ __forceinline__ bf16x8 pack8(float4 a, float4 b) {
    bf16x8 o;
    o[0] = (short)f2bf(a.x); o[1] = (short)f2bf(a.y);
    o[2] = (short)f2bf(a.z); o[3] = (short)f2bf(a.w);
    o[4] = (short)f2bf(b.x); o[5] = (short)f2bf(b.y);
    o[6] = (short)f2bf(b.z); o[7] = (short)f2bf(b.w);
    return o;
}

// ws layout (bytes):
//   [0, 1MB)            : Wbf  bf16 [512][1024]  (We: row n=d, col k=e, k-contiguous)
//   [1MB, 1MB+64KB)     : hb   f32  [32][512]    (h_proj + bias)
//   [1MB+64KB, +256KB)  : scores f32 [32][2048]  (written directly by eproj)
#define WS_WBF   0
#define WS_HB    (1u << 20)
#define WS_SCORE ((1u << 20) + (64u << 10))

// ---- prep: convert We->bf16 (blocks 0..511), hproj (blocks 512..575) ----
__global__ void prep_kernel(const float* __restrict__ W,
                            const float* __restrict__ hidden,
                            const float* __restrict__ bias,
                            ushort* __restrict__ Wbf,
                            float* __restrict__ hb) {
    const int bid = blockIdx.x, tid = threadIdx.x;
    if (bid < 512) {
        int idx = bid * 256 + tid;
        int d  = idx >> 8;
        int e4 = (idx & 255) * 4;
        float4 f = *(const float4*)(W + (size_t)d * 1536 + 512 + e4);
        ushort4 u;
        u.x = f2bf(f.x); u.y = f2bf(f.y); u.z = f2bf(f.z); u.w = f2bf(f.w);
        *(ushort4*)(Wbf + (size_t)d * 1024 + e4) = u;
    } else {
        int idx = (bid - 512) * 256 + tid;        // 0..16383 = 32*512
        int b = idx >> 9, d = idx & 511;
        const float4* hp = (const float4*)(hidden + b * 512);
        const float4* wp = (const float4*)(W + (size_t)d * 1536);
        float acc = 0.f;
#pragma unroll 8
        for (int j = 0; j < 128; ++j) {
            float4 h = hp[j], w = wp[j];
            acc += h.x * w.x + h.y * w.y + h.z * w.z + h.w * w.w;
        }
        hb[idx] = acc + bias[d];
    }
}

// ---- main: e_proj GEMM (M=65536,N=512,K=1024) fused tanh + v-dot -> scores ----
// Round-5 post-mortem: FIVE schedules (drain-barrier, spilled, counted-wait,
// BN=512, slack-deepened) all 204-236us. The invariant: HBM delivery rate
// 627-700 GB/s in r1-r5 -- vs r0's 1.32 TB/s. r0 fetched 512B CONTIGUOUS per
// enc row per issue window; r1-r5 fetch 128B/row (BK=32) strided 4KB. 64
// scattered 128B touches per CU per kt across 256 CUs kills DRAM page
// locality; HBM efficiency ~8% of peak. Iter time = 8KB/kt / ~2.6 B/cy/CU =
// 3-4K cy -- exactly measured. Every schedule preserved the pattern, so
// every schedule tied.
//
// Fix: window-based staging, 1KB contiguous per row per window.
//   * Window = 64 rows x 256 f32 (8 kt). LDS = 2 windows x 64KB f32 = 128KB
//     (dynamic; 1 block/CU). Staged via global_load_lds dwordx4 (f32 -- no
//     cvt at stage; pack8 at read, VALU is only 12% busy).
//   * DMA issue order row-batched: each instruction's 64 lanes cover exactly
//     ONE full 1KB row (chunk-XOR-swizzled within the row) = 16 consecutive
//     64B lines per burst. DRAM-friendly.
//   * ONE counted vmcnt + 2 barriers per 8 kt (was per-kt). At window w's
//     head, in-order queue = [... older ..., DMA(w+1) newest 8] so
//     s_waitcnt vmcnt(8) forces exactly "everything through DMA(w)" done.
//     DMA(w+2) issued after the post-consume barrier -> a full window
//     (~2-3K cy) of compute covers its latency. Never vmcnt(0) mid-loop.
//   * Chunk swizzle: LDS chunk c of row r holds global chunk c^(r&7); reads
//     of 16 rows at fixed chunk spread over 8 bank-starts -> <=2-way (free).
//   * B: reg double-buffer bfr[2][4], L2-hot; kt&1 is compile-time (j&1).
__launch_bounds__(512, 2)
__global__ void eproj_scores(const float* __restrict__ enc,
                             const ushort* __restrict__ Wbf,
                             const float* __restrict__ hb,
                             const float* __restrict__ v,
                             float* __restrict__ scores) {
    extern __shared__ float Abuf[];                // [2][64][256] f32 = 128KB

    const int tid  = threadIdx.x;
    const int lane = tid & 63, w = tid >> 6;       // 8 waves
    const int q = lane >> 4, ln = lane & 15;
    const long m0   = (long)blockIdx.x * 64;
    const int  bidx = (int)(m0 >> 11);             // 32 M-blocks per batch row
    const int  n0   = w * 64;                      // wave's 64-col slice of N=512

    f32x4 acc[4][4];
#pragma unroll
    for (int mt = 0; mt < 4; ++mt)
#pragma unroll
        for (int nt = 0; nt < 4; ++nt)
            acc[mt][nt] = (f32x4){0.f, 0.f, 0.f, 0.f};

    // B row pointers (per nt); k advances 32 bf16 per kt
    const ushort* bptr[4];
#pragma unroll
    for (int nt = 0; nt < 4; ++nt)
        bptr[nt] = Wbf + (size_t)(n0 + nt * 16 + ln) * 1024 + q * 8;

    // DMA one window wi (K-slice wi*256..+256 f32) into LDS half wi&1.
    // slot s = i*512+tid: r = s>>6 (row), c = s&63 (16B chunk in row's 1KB).
    // Wave wv at batch i covers slots (i*512+wv*64)..+63 = ONE full row.
    // Source chunk cg = c ^ (r&7)  (read side applies the same XOR).
    auto dma_window = [&](int wi) {
        float* base = Abuf + (size_t)(wi & 1) * 16384;
#pragma unroll
        for (int i = 0; i < 8; ++i) {
            int s = i * 512 + tid;
            int r = s >> 6, c = s & 63;
            int cg = c ^ (r & 7);
            const float* g = enc + (m0 + r) * 1024 + wi * 256 + cg * 4;
            float* lb = base + (size_t)s * 4;      // wave-uniform base + lane*16B
            __builtin_amdgcn_global_load_lds(
                (const __attribute__((address_space(1))) void*)g,
                (__attribute__((address_space(3))) void*)lb, 16, 0, 0);
        }
    };

    // ---- prologue: DMA windows 0,1; B(0) frags ----
    dma_window(0);
    dma_window(1);
    bf16x8 bfr[2][4];
#pragma unroll
    for (int nt = 0; nt < 4; ++nt)
        bfr[0][nt] = *(const bf16x8*)(bptr[nt]);

    // per-mt row constants
    int rA[4], rx[4];
#pragma unroll
    for (int mt = 0; mt < 4; ++mt) {
        rA[mt] = mt * 16 + ln;
        rx[mt] = rA[mt] & 7;
    }

    // ---- window loop: 4 windows x 8 kt ----
    for (int wi = 0; wi < 4; ++wi) {
        // head: ensure window wi's DMA landed (all waves), keep wi+1 in flight
        if (wi < 3) asm volatile("s_waitcnt vmcnt(8)" ::: "memory");
        else        asm volatile("s_waitcnt vmcnt(0)" ::: "memory");
        __builtin_amdgcn_s_barrier();
        asm volatile("" ::: "memory");

        const float* AW = Abuf + (size_t)(wi & 1) * 16384;
#pragma unroll
        for (int j = 0; j < 8; ++j) {
            const int kt = wi * 8 + j;
            // B prefetch for kt+1 (issued before MFMA waits; L2-hot)
            if (wi < 3 || j < 7) {
#pragma unroll
                for (int nt = 0; nt < 4; ++nt)
                    bfr[(j + 1) & 1][nt] =
                        *(const bf16x8*)(bptr[nt] + (size_t)(kt + 1) * 32);
            }
#pragma unroll
            for (int mt = 0; mt < 4; ++mt) {
                const float* Ar = AW + rA[mt] * 256;
                int c0 = j * 8 + q * 2;            // 16B chunk index (compile-time j)
                float4 a0 = *(const float4*)(Ar + ((c0    ) ^ rx[mt]) * 4);
                float4 a1 = *(const float4*)(Ar + ((c0 + 1) ^ rx[mt]) * 4);
                bf16x8 af = pack8(a0, a1);
#pragma unroll
                for (int nt = 0; nt < 4; ++nt)
                    acc[mt][nt] = __builtin_amdgcn_mfma_f32_16x16x32_bf16(
                        af, bfr[j & 1][nt], acc[mt][nt], 0, 0, 0);
            }
        }

        // all waves done reading half wi&1 (ds_reads consumed by MFMAs above)
        __builtin_amdgcn_s_barrier();
        asm volatile("" ::: "memory");
        if (wi + 2 < 4) dma_window(wi + 2);        // overwrite half wi&1
    }

    // epilogue: energy = tanh(acc + hb), partial = sum_d v[d]*energy (wave slice)
    float partial[4][4];
#pragma unroll
    for (int mt = 0; mt < 4; ++mt)
#pragma unroll
        for (int r = 0; r < 4; ++r) partial[mt][r] = 0.f;

#pragma unroll
    for (int nt = 0; nt < 4; ++nt) {
        int d = n0 + nt * 16 + ln;
        float hbv = hb[bidx * 512 + d];
        float vv  = v[d];
#pragma unroll
        for (int mt = 0; mt < 4; ++mt)
#pragma unroll
            for (int r = 0; r < 4; ++r) {
                float x = acc[mt][nt][r] + hbv;
                float e = __expf(2.f * x);          // tanh(x) = 1 - 2/(e^{2x}+1)
                partial[mt][r] += vv * (1.f - 2.f / (e + 1.f));
            }
    }
#pragma unroll
    for (int mt = 0; mt < 4; ++mt)
#pragma unroll
        for (int r = 0; r < 4; ++r) {
            float s = partial[mt][r];
            s += __shfl_xor(s, 1);
            s += __shfl_xor(s, 2);
            s += __shfl_xor(s, 4);
            s += __shfl_xor(s, 8);
            partial[mt][r] = s;
        }

    __syncthreads();                     // all LDS reads done; reuse Abuf for spart
    float* spart = Abuf;                 // [8][64]
    if (ln == 0) {
#pragma unroll
        for (int mt = 0; mt < 4; ++mt)
#pragma unroll
            for (int r = 0; r < 4; ++r)
                spart[w * 64 + mt * 16 + q * 4 + r] = partial[mt][r];
    }
    __syncthreads();
    if (tid < 64) {
        float s = 0.f;
#pragma unroll
        for (int ww = 0; ww < 8; ++ww) s += spart[ww * 64 + tid];
        scores[m0 + tid] = s;            // direct store: block covers all d
    }
}

// ---- softmax over S=2048 per b ----
__global__ void softmax_kernel(const float* __restrict__ scores, float* __restrict__ out) {
    int b = blockIdx.x;
    const float* sc = scores + b * 2048;
    __shared__ float wred[4], wsum[4];

    float lmax = -1e30f;
    for (int i = threadIdx.x; i < 2048; i += 256) lmax = fmaxf(lmax, sc[i]);
#pragma unroll
    for (int m = 1; m < 64; m <<= 1) lmax = fmaxf(lmax, __shfl_xor(lmax, m));
    if ((threadIdx.x & 63) == 0) wred[threadIdx.x >> 6] = lmax;
    __syncthreads();
    float gmax = fmaxf(fmaxf(wred[0], wred[1]), fmaxf(wred[2], wred[3]));

    float lsum = 0.f;
    for (int i = threadIdx.x; i < 2048; i += 256) lsum += __expf(sc[i] - gmax);
#pragma unroll
    for (int m = 1; m < 64; m <<= 1) lsum += __shfl_xor(lsum, m);
    if ((threadIdx.x & 63) == 0) wsum[threadIdx.x >> 6] = lsum;
    __syncthreads();
    float inv = 1.f / (wsum[0] + wsum[1] + wsum[2] + wsum[3]);

    for (int i = threadIdx.x; i < 2048; i += 256)
        out[b * 2048 + i] = __expf(sc[i] - gmax) * inv;
}

extern "C" void kernel_launch(void* const* d_in, const int* in_sizes, int n_in,
                              void* d_out, int out_size, void* d_ws, size_t ws_size,
                              hipStream_t stream) {
    const float* hidden = (const float*)d_in[0];   // 32 x 512
    const float* enc    = (const float*)d_in[1];   // 32 x 2048 x 1024
    const float* W      = (const float*)d_in[2];   // 512 x 1536
    const float* bias   = (const float*)d_in[3];   // 512
    const float* v      = (const float*)d_in[4];   // 512
    float* out = (float*)d_out;                    // 32 x 1 x 2048

    char* ws = (char*)d_ws;
    ushort* Wbf   = (ushort*)(ws + WS_WBF);
    float*  hb    = (float*)(ws + WS_HB);
    float*  score = (float*)(ws + WS_SCORE);

    hipLaunchKernelGGL(prep_kernel,  dim3(576),  dim3(256), 0, stream,
                       W, hidden, bias, Wbf, hb);
    hipLaunchKernelGGL(eproj_scores, dim3(1024), dim3(512), 131072, stream,
                       enc, Wbf, hb, v, score);
    hipLaunchKernelGGL(softmax_kernel, dim3(32), dim3(256), 0, stream, score, out);
}